// Round 4
// baseline (1159.936 us; speedup 1.0000x reference)
//
#include <hip/hip_runtime.h>
#include <stdint.h>

#define N_SEQ 16384
#define T_LEN 16
#define E_DIM 256
#define H_DIM 256
#define K_DIM 512
#define B_SAMP 128
#define V_SIZE 10000

typedef __bf16 bf16x8 __attribute__((ext_vector_type(8)));
typedef float  f32x4  __attribute__((ext_vector_type(4)));
typedef unsigned short u16x8 __attribute__((ext_vector_type(8)));
typedef unsigned short ush;

__device__ __forceinline__ ush f2bf(float x) {
  unsigned int u = __float_as_uint(x);
  u = (u + 0x7fffu + ((u >> 16) & 1u)) >> 16;
  return (ush)u;
}
__device__ __forceinline__ float bf2f(ush v) {
  return __uint_as_float(((unsigned int)v) << 16);
}
__device__ __forceinline__ float sigmoidf_(float x) {
  return 1.0f / (1.0f + __expf(-x));
}
__device__ __forceinline__ float tanhf_(float x) {
  float e = __expf(2.0f * x);
  return 1.0f - 2.0f / (e + 1.0f);
}
__device__ __forceinline__ void glds16(const void* g, const void* l) {
  __builtin_amdgcn_global_load_lds(
      (const __attribute__((address_space(1))) unsigned int*)g,
      (__attribute__((address_space(3))) unsigned int*)l, 16, 0, 0);
}

// ---------------- prep kernels ----------------

__global__ __launch_bounds__(256) void k_lens(const int* __restrict__ tok, int* __restrict__ lens) {
  int n = blockIdx.x * 256 + threadIdx.x;
  const int* r = tok + n * T_LEN;
  int c = 0;
#pragma unroll
  for (int t = 0; t < T_LEN; ++t) c += (r[t] != 0);
  lens[n] = c;
}

__global__ __launch_bounds__(256) void k_hist(const int* __restrict__ lens, int* __restrict__ hist) {
  __shared__ int lh[17];
  if (threadIdx.x < 17) lh[threadIdx.x] = 0;
  __syncthreads();
  atomicAdd(&lh[lens[blockIdx.x * 256 + threadIdx.x]], 1);
  __syncthreads();
  if (threadIdx.x < 17) atomicAdd(&hist[threadIdx.x], lh[threadIdx.x]);
}

__global__ void k_offsets(const int* __restrict__ hist, int* __restrict__ cursor) {
  if (threadIdx.x == 0) {
    int off = 0;
    for (int l = 16; l >= 0; --l) { cursor[l] = off; off += hist[l]; }
  }
}

__global__ __launch_bounds__(256) void k_scatter(const int* __restrict__ lens, int* __restrict__ cursor,
                                                 int* __restrict__ perm, int* __restrict__ pinv,
                                                 int* __restrict__ plens) {
  int n = blockIdx.x * 256 + threadIdx.x;
  int l = lens[n];
  int pos = atomicAdd(&cursor[l], 1);
  perm[pos] = n;
  pinv[n] = pos;
  plens[pos] = l;
}

__global__ __launch_bounds__(256) void k_embcvt(const float* __restrict__ emb, ush* __restrict__ out) {
  int i = blockIdx.x * 256 + threadIdx.x;
  out[i] = f2bf(emb[i]);
}

// Permuted weights: wpt[p][k], p = nc*256 + w*64 + q*16 + jj  <->
// gate-row r = q*256 + (nc*64 + w*16 + jj);  k<256 -> W_ih[r][k], else W_hh[r][k-256].
__global__ __launch_bounds__(256) void k_wprep(const float* __restrict__ Wih_f, const float* __restrict__ Whh_f,
                                               const float* __restrict__ Wih_b, const float* __restrict__ Whh_b,
                                               ush* __restrict__ wpt_f, ush* __restrict__ wpt_b) {
  int id = blockIdx.x * 256 + threadIdx.x;  // < 2*1024*512
  int dir = id >> 19;
  int rem = id & ((1 << 19) - 1);
  int p = rem >> 9;
  int k = rem & 511;
  int nc = p >> 8, w = (p >> 6) & 3, q = (p >> 4) & 3, jj = p & 15;
  int r = q * 256 + nc * 64 + w * 16 + jj;
  const float* Wih = dir ? Wih_b : Wih_f;
  const float* Whh = dir ? Whh_b : Whh_f;
  float v = (k < 256) ? Wih[r * 256 + k] : Whh[r * 256 + (k - 256)];
  ush* o = dir ? wpt_b : wpt_f;
  o[p * 512 + k] = f2bf(v);
}

// ---------------- persistent LSTM: all 16 steps in one dispatch ----------------
// 512 blocks (256 row-tiles x 2 dirs, balance-paired), 256 threads (4 waves).
// Block owns 64 sorted rows; runs t=0..maxlen-1 (fwd) or reversed (bwd).
// Per step: [flush deferred h][stage x via glds16] barrier; then 4 nc x 16 kc
// wave-private phases: 4 global B-frag loads + 4 LDS A-frag reads + 16 MFMA.
// h in LDS (XOR-swizzled), c in VGPRs, new-h deferred in regs to next step head.

__global__ __launch_bounds__(256, 2)
void k_lstm(const ush* __restrict__ embbf, const int* __restrict__ tok,
            const int* __restrict__ perm, const int* __restrict__ plens,
            const ush* __restrict__ wpt_f, const ush* __restrict__ wpt_b,
            const float* __restrict__ bias_f, const float* __restrict__ bias_b,
            ush* __restrict__ hfin_f, ush* __restrict__ hfin_b) {
  const int bi = blockIdx.x;
  int rb, dir;
  if (bi < 256) { rb = bi; dir = bi & 1; }
  else          { rb = 511 - bi; dir = 1 - (rb & 1); }  // pair long rank k with rank 255-k per CU
  const int m0 = rb * 64;
  const ush* wpt = dir ? wpt_b : wpt_f;
  const float* bias = dir ? bias_b : bias_f;
  ush* hfin = dir ? hfin_b : hfin_f;

  __shared__ __align__(128) ush xs[64 * 256];  // 32 KB, x_t staged per step
  __shared__ __align__(128) ush hs[64 * 256];  // 32 KB, recurrent h

  const int tid = threadIdx.x;
  const int lane = tid & 63;
  const int w = tid >> 6;
  const int frow = lane & 15, fkq = lane >> 4;
  const int maxlen = plens[m0];  // rows sorted descending -> first row has block max

  // per-lane cached lens: n = fr*16 + fkq*4 + r
  int4 ln[4];
#pragma unroll
  for (int fr = 0; fr < 4; ++fr) ln[fr] = *(const int4*)&plens[m0 + fr * 16 + fkq * 4];

  // zero h
  {
    u16x8 z = {};
#pragma unroll
    for (int i = 0; i < 8; ++i) *(u16x8*)&hs[(i * 256 + tid) * 8] = z;
  }
  f32x4 c4[4][4] = {};  // [nc][fr], r in vector lanes
  uint2 hn[4][4];       // deferred new-h, 4 bf16 packed per [nc][fr]

  const int xrow_base = w * 16 + (lane >> 5);  // + q*2
  const int xch = lane & 31;
  const int jl = w * 16 + frow;  // hidden j = nc*64 + jl

  auto flushh = [&](int tp) {
#pragma unroll
    for (int nc = 0; nc < 4; ++nc) {
      const int j = nc * 64 + jl;
      const int hch = j >> 3, jb = j & 7;
#pragma unroll
      for (int fr = 0; fr < 4; ++fr) {
        const int nl = fr * 16 + fkq * 4;
        const uint2 pk = hn[nc][fr];
        if (tp < ln[fr].x) hs[(nl + 0) * 256 + ((hch ^ ((nl + 0) & 7)) * 8) + jb] = (ush)(pk.x & 0xffffu);
        if (tp < ln[fr].y) hs[(nl + 1) * 256 + ((hch ^ ((nl + 1) & 7)) * 8) + jb] = (ush)(pk.x >> 16);
        if (tp < ln[fr].z) hs[(nl + 2) * 256 + ((hch ^ ((nl + 2) & 7)) * 8) + jb] = (ush)(pk.y & 0xffffu);
        if (tp < ln[fr].w) hs[(nl + 3) * 256 + ((hch ^ ((nl + 3) & 7)) * 8) + jb] = (ush)(pk.y >> 16);
      }
    }
  };

  for (int s = 0; s < maxlen; ++s) {
    const int t = dir ? (maxlen - 1 - s) : s;
    __syncthreads();  // all waves done reading hs/xs of previous step
    if (s > 0) flushh(dir ? (maxlen - s) : (s - 1));
    // stage x_t: 8 glds16 per thread, pre-swizzled source, linear LDS dest
#pragma unroll
    for (int q = 0; q < 8; ++q) {
      const int row = xrow_base + q * 2;
      const int pn = perm[m0 + row];
      const int tokv = tok[pn * T_LEN + t];
      glds16(embbf + (size_t)tokv * 256 + ((xch ^ (row & 7)) * 8), xs + (w * 8 + q) * 512);
    }
    __syncthreads();  // x + flushed h visible (vmcnt drained by barrier)

#pragma unroll
    for (int nc = 0; nc < 4; ++nc) {
      const int j = nc * 64 + jl;
      f32x4 acc[4][4];
#pragma unroll
      for (int q = 0; q < 4; ++q) {
        const float bq = bias[q * 256 + j];
#pragma unroll
        for (int fr = 0; fr < 4; ++fr) acc[fr][q] = f32x4{bq, bq, bq, bq};
      }
#pragma unroll 2
      for (int kc = 0; kc < 16; ++kc) {
        bf16x8 bv[4];
#pragma unroll
        for (int q = 0; q < 4; ++q) {
          const int prow = nc * 256 + w * 64 + q * 16 + frow;
          bv[q] = *(const bf16x8*)&wpt[(size_t)prow * 512 + kc * 32 + fkq * 8];
        }
        bf16x8 av[4];
        const ush* abase = (kc < 8) ? xs : hs;
        const int kcl = kc & 7;
#pragma unroll
        for (int fr = 0; fr < 4; ++fr) {
          const int row = fr * 16 + frow;
          const int cch = (kcl * 4 + fkq) ^ (row & 7);
          av[fr] = *(const bf16x8*)&abase[row * 256 + cch * 8];
        }
#pragma unroll
        for (int fr = 0; fr < 4; ++fr)
#pragma unroll
          for (int q = 0; q < 4; ++q)
            acc[fr][q] = __builtin_amdgcn_mfma_f32_16x16x32_bf16(av[fr], bv[q], acc[fr][q], 0, 0, 0);
      }
      // cell update -> c4, deferred hn
#pragma unroll
      for (int fr = 0; fr < 4; ++fr) {
        unsigned int pk0 = 0, pk1 = 0;
#pragma unroll
        for (int r = 0; r < 4; ++r) {
          const int lnv = (r == 0) ? ln[fr].x : (r == 1) ? ln[fr].y : (r == 2) ? ln[fr].z : ln[fr].w;
          float hv = 0.0f;
          if (t < lnv) {
            const float iv = sigmoidf_(acc[fr][0][r]);
            const float fv = sigmoidf_(acc[fr][1][r]);
            const float gv = tanhf_(acc[fr][2][r]);
            const float ov = sigmoidf_(acc[fr][3][r]);
            const float cn = fv * c4[nc][fr][r] + iv * gv;
            c4[nc][fr][r] = cn;
            hv = ov * tanhf_(cn);
          }
          const unsigned int hb = f2bf(hv);
          if (r == 0) pk0 |= hb;
          else if (r == 1) pk0 |= hb << 16;
          else if (r == 2) pk1 |= hb;
          else pk1 |= hb << 16;
        }
        hn[nc][fr] = make_uint2(pk0, pk1);
      }
    }
  }

  // final flush + coalesced writeout of h
  __syncthreads();
  flushh(dir ? 0 : (maxlen - 1));
  __syncthreads();
#pragma unroll
  for (int i = 0; i < 8; ++i) {
    const int g = i * 256 + tid;
    const int row = g >> 5, ch = g & 31;
    u16x8 v = *(const u16x8*)&hs[row * 256 + ((ch ^ (row & 7)) * 8)];
    *(u16x8*)&hfin[(size_t)(m0 + row) * 256 + ch * 8] = v;
  }
}

// ---------------- segment-mean pool (before the linear layer) ----------------

__global__ __launch_bounds__(256) void k_pool(const ush* __restrict__ hf,
                                              const ush* __restrict__ hb,
                                              const int* __restrict__ pinv,
                                              const int* __restrict__ plen,
                                              float* __restrict__ pooled) {
  const int b = blockIdx.x, tid = threadIdx.x;
  int start = 0;
  for (int i = 0; i < b; ++i) start += plen[i];
  const int cnt = plen[b];
  float s0 = 0.f, s1 = 0.f;
  for (int r = 0; r < cnt; ++r) {
    const size_t pr = (size_t)pinv[start + r];
    s0 += bf2f(hf[pr * H_DIM + tid]);
    s1 += bf2f(hb[pr * H_DIM + tid]);
  }
  float inv = 1.0f / (float)cnt;
  pooled[b * 512 + tid] = s0 * inv;
  pooled[b * 512 + H_DIM + tid] = s1 * inv;
}

// ---------------- tiny linear (128x512x512) + L2 normalize, f32 ----------------

__global__ __launch_bounds__(256) void k_final(const float* __restrict__ pooled,
                                               const float* __restrict__ W,
                                               const float* __restrict__ bl,
                                               float* __restrict__ out) {
  const int b = blockIdx.x, tid = threadIdx.x;
  __shared__ float pv[512];
  __shared__ float pre[512];
  __shared__ float red[4];
  pv[tid] = pooled[b * 512 + tid];
  pv[tid + 256] = pooled[b * 512 + 256 + tid];
  __syncthreads();
#pragma unroll
  for (int half = 0; half < 2; ++half) {
    const int dd = tid + half * 256;
    const f32x4* wr = (const f32x4*)(W + (size_t)dd * 512);
    const f32x4* pvv = (const f32x4*)pv;
    float s = bl[dd];
#pragma unroll 4
    for (int k4 = 0; k4 < 128; ++k4) {
      f32x4 wv = wr[k4], xv = pvv[k4];
      s += wv[0] * xv[0] + wv[1] * xv[1] + wv[2] * xv[2] + wv[3] * xv[3];
    }
    pre[dd] = s;
  }
  __syncthreads();
  float ss = pre[tid] * pre[tid] + pre[tid + 256] * pre[tid + 256];
#pragma unroll
  for (int off = 32; off > 0; off >>= 1) ss += __shfl_down(ss, off, 64);
  if ((tid & 63) == 0) red[tid >> 6] = ss;
  __syncthreads();
  float tot = red[0] + red[1] + red[2] + red[3];
  float scale = 1.0f / fmaxf(sqrtf(tot), 1e-5f);
  out[b * 512 + tid] = pre[tid] * scale;
  out[b * 512 + 256 + tid] = pre[tid + 256] * scale;
}

// ---------------- launch ----------------

extern "C" void kernel_launch(void* const* d_in, const int* in_sizes, int n_in,
                              void* d_out, int out_size, void* d_ws, size_t ws_size,
                              hipStream_t stream) {
  const int* tok    = (const int*)d_in[0];
  const int* plen   = (const int*)d_in[1];
  const float* emb  = (const float*)d_in[2];
  const float* Wih_f = (const float*)d_in[3];
  const float* Whh_f = (const float*)d_in[4];
  const float* b_f   = (const float*)d_in[5];
  const float* Wih_b = (const float*)d_in[6];
  const float* Whh_b = (const float*)d_in[7];
  const float* b_b   = (const float*)d_in[8];
  const float* Wlin  = (const float*)d_in[9];
  const float* blin  = (const float*)d_in[10];
  float* out = (float*)d_out;

  char* ws = (char*)d_ws;
  size_t off = 0;
  auto alloc = [&](size_t bytes) {
    void* p = ws + off;
    off = (off + bytes + 255) & ~(size_t)255;
    return p;
  };
  ush* embbf = (ush*)alloc((size_t)V_SIZE * E_DIM * 2);
  ush* wptf  = (ush*)alloc((size_t)1024 * K_DIM * 2);
  ush* wptb  = (ush*)alloc((size_t)1024 * K_DIM * 2);
  int* lens  = (int*)alloc((size_t)N_SEQ * 4);
  int* perm  = (int*)alloc((size_t)N_SEQ * 4);
  int* pinv  = (int*)alloc((size_t)N_SEQ * 4);
  int* plens = (int*)alloc((size_t)N_SEQ * 4);
  int* hist  = (int*)alloc(17 * 4);
  int* cursor = (int*)alloc(17 * 4);
  ush* hfinf = (ush*)alloc((size_t)N_SEQ * H_DIM * 2);
  ush* hfinb = (ush*)alloc((size_t)N_SEQ * H_DIM * 2);
  float* pooled = (float*)alloc((size_t)B_SAMP * 512 * 4);

  hipMemsetAsync(hist, 0, 17 * 4, stream);

  k_lens<<<N_SEQ / 256, 256, 0, stream>>>(tok, lens);
  k_hist<<<N_SEQ / 256, 256, 0, stream>>>(lens, hist);
  k_offsets<<<1, 64, 0, stream>>>(hist, cursor);
  k_scatter<<<N_SEQ / 256, 256, 0, stream>>>(lens, cursor, perm, pinv, plens);
  k_embcvt<<<(V_SIZE * E_DIM) / 256, 256, 0, stream>>>(emb, embbf);
  k_wprep<<<(2 * 1024 * K_DIM) / 256, 256, 0, stream>>>(Wih_f, Whh_f, Wih_b, Whh_b, wptf, wptb);

  k_lstm<<<512, 256, 0, stream>>>(embbf, tok, perm, plens, wptf, wptb, b_f, b_b, hfinf, hfinb);

  k_pool<<<B_SAMP, 256, 0, stream>>>(hfinf, hfinb, pinv, plen, pooled);
  k_final<<<B_SAMP, 256, 0, stream>>>(pooled, Wlin, blin, out);
}